// Round 14
// baseline (264.733 us; speedup 1.0000x reference)
//
#include <hip/hip_runtime.h>

typedef unsigned short u16;
typedef unsigned int   u32;
typedef _Float16 f16x8 __attribute__((ext_vector_type(8)));
typedef __fp16   hf2   __attribute__((ext_vector_type(2)));
typedef float    f32x4 __attribute__((ext_vector_type(4)));

#define NTOK 49
#define CDIM 192
#define NH   6
#define HD   32
#define SC   0.17677669529663687f
#define LOG2E 1.4426950408889634f

// ---- LDS arena (u16 units) ----
// x fp32 (49x192 = 37,632 B, granule-swizzled) overlays Q+K regions during staging;
// consumed into registers before QKV writes (extra barrier).
#define QOFF   0
#define QSTR   200            // 400 B stride
#define KOFF   9800
#define VTOFF  19600
#define VTSTR  56             // 112 B
#define POFF   30352          // per-wave P ping-pong: wv*2336 + (h&1)*1168
#define PSTR   72
#define ARENA_U16 40152       // 80,304 B -> 2 blocks/CU

// ---- ws layout (u16 units) ----
#define WS_WQ 0               // qkv weights frag-major: [(t*6+k6)*512 + lane*8 + e]; Q pre-scaled by SC*LOG2E
#define WS_WP 110592          // proj weights, same scheme
#define WS_BM 147456          // bias+mask per-thread (x LOG2E): [w][h][tid(256)][jt(4)][r(4)]

static __device__ __forceinline__ u16 f2h(float f){ union{ _Float16 h; u16 u;} v; v.h=(_Float16)f; return v.u; }
static __device__ __forceinline__ u32 pk2(float a, float b){
    hf2 h = __builtin_amdgcn_cvt_pkrtz(a, b);
    return __builtin_bit_cast(u32, h);
}
static __device__ __forceinline__ void gload16(const float* g, u16* l){
    __builtin_amdgcn_global_load_lds(
        (const __attribute__((address_space(1))) unsigned int*)g,
        (__attribute__((address_space(3))) unsigned int*)l, 16, 0, 0);
}

// ---------------- prep ----------------
__global__ void prep_weights(const float* __restrict__ qkv_w,
                             const float* __restrict__ proj_w,
                             u16* __restrict__ ws)
{
    const int idx = blockIdx.x*256 + threadIdx.x;
    if (idx < 110592) {
        const int fid = idx >> 9, r = idx & 511;
        const int lane = r >> 3, e = r & 7;
        const int t = fid/6, k6 = fid - 6*t;
        const int col = t*16 + (lane & 15);
        const int kk  = k6*32 + (lane >> 4)*8 + e;
        float w = qkv_w[col*CDIM + kk];
        if (col < CDIM) w *= SC * LOG2E;    // fold softmax scale + log2e into Q weights
        ws[WS_WQ + idx] = f2h(w);
    } else if (idx < 147456) {
        const int j = idx - 110592;
        const int fid = j >> 9, r = j & 511;
        const int lane = r >> 3, e = r & 7;
        const int t = fid/6, k6 = fid - 6*t;
        const int col = t*16 + (lane & 15);
        const int kk  = k6*32 + (lane >> 4)*8 + e;
        ws[WS_WP + j] = f2h(proj_w[col*CDIM + kk]);
    }
}

// thread tid of wave wv handles q-row i=16*(tid>>6)+(tid&15), j = jt*16 + 4*((tid>>4)&3) + r
__global__ void prep_bm(const float* __restrict__ mask,
                        const float* __restrict__ rpb,
                        const int*   __restrict__ rel,
                        u16* __restrict__ ws)
{
    const int idx = blockIdx.x*256 + threadIdx.x;
    if (idx >= 64*NH*256*16) return;
    const int r   = idx & 3;
    const int jt  = (idx >> 2) & 3;
    const int tid = (idx >> 4) & 255;
    const int rest = idx >> 12;
    const int h = rest % NH;
    const int w = rest / NH;
    const int i  = 16*(tid >> 6) + (tid & 15);
    const int lg = (tid >> 4) & 3;
    const int j  = jt*16 + 4*lg + r;
    float v;
    if (i >= NTOK)      v = 0.0f;
    else if (j >= NTOK) v = -1e30f;        // -> fp16 -inf; exp2 -> 0
    else v = (rpb[rel[i*NTOK+j]*NH + h] + mask[((size_t)w*NTOK+i)*NTOK + j]) * LOG2E;
    ws[WS_BM + idx] = f2h(v);
}

// ---------------- fused core ----------------
#define LDFRAG(B, BASE, t) { const u16* _p = (BASE) + (size_t)(t)*3072 + lane*8;      \
    B[0]=*(const f16x8*)(_p);      B[1]=*(const f16x8*)(_p+512);                      \
    B[2]=*(const f16x8*)(_p+1024); B[3]=*(const f16x8*)(_p+1536);                     \
    B[4]=*(const f16x8*)(_p+2048); B[5]=*(const f16x8*)(_p+2560); }

#define QKV_STEP(s, CUR, NXT, PF) {                                                   \
    if (PF) { LDFRAG(NXT, wq, t0+(s)+2); }                                            \
    const int _t = t0+(s); const int _sec = _t/12; const int _cb = (_t - _sec*12)*16; \
    f32x4 _ac[4];                                                                     \
    if (_sec < 2) {  /* Q/K swapped: token=lane, channel=reg; bias in acc-init */     \
      float4 _b4 = *(const float4*)&qkv_b[_t*16 + 4*lg];                              \
      if (_sec == 0) { _b4.x*=SC*LOG2E; _b4.y*=SC*LOG2E; _b4.z*=SC*LOG2E; _b4.w*=SC*LOG2E; } \
      const f32x4 _ini = {_b4.x, _b4.y, _b4.z, _b4.w};                                \
      _ac[0]=_ini; _ac[1]=_ini; _ac[2]=_ini; _ac[3]=_ini;                             \
      _Pragma("unroll") for (int _k=0;_k<6;++_k)                                      \
        _Pragma("unroll") for (int _m=0;_m<4;++_m)                                    \
          _ac[_m] = __builtin_amdgcn_mfma_f32_16x16x32_f16(CUR[_k], A[_k][_m], _ac[_m],0,0,0); \
      u16* _dst = (_sec==0) ? (arena+QOFF) : (arena+KOFF);                            \
      _Pragma("unroll") for (int _m=0;_m<4;++_m) {                                    \
        const int _tok = 16*_m + l15;                                                 \
        if (_tok < NTOK) {                                                            \
          uint2 _wd = make_uint2(pk2(_ac[_m][0], _ac[_m][1]),                         \
                                 pk2(_ac[_m][2], _ac[_m][3]));                        \
          *(uint2*)&_dst[_tok*QSTR + _cb + 4*lg] = _wd; } }                           \
    } else {         /* V normal: token=reg -> packed V^T writes */                   \
      const float _b1 = qkv_b[384 + _cb + l15];                                       \
      const f32x4 _ini = {_b1, _b1, _b1, _b1};                                        \
      _ac[0]=_ini; _ac[1]=_ini; _ac[2]=_ini; _ac[3]=_ini;                             \
      _Pragma("unroll") for (int _k=0;_k<6;++_k)                                      \
        _Pragma("unroll") for (int _m=0;_m<4;++_m)                                    \
          _ac[_m] = __builtin_amdgcn_mfma_f32_16x16x32_f16(A[_k][_m], CUR[_k], _ac[_m],0,0,0); \
      _Pragma("unroll") for (int _m=0;_m<4;++_m) {                                    \
        if (16*_m + 4*lg <= 48) {                                                     \
          uint2 _wd = make_uint2(pk2(_ac[_m][0], _ac[_m][1]),                         \
                                 pk2(_ac[_m][2], _ac[_m][3]));                        \
          *(uint2*)&arena[VTOFF + (_cb + l15)*VTSTR + 16*_m + 4*lg] = _wd; } } } }

#define PROJ_STEP(s, CUR, NXT, PF) {                                                  \
    if (PF) { LDFRAG(NXT, wp, p0+(s)+1); }                                            \
    const f32x4 _ini = {pb4[s].x, pb4[s].y, pb4[s].z, pb4[s].w};                      \
    f32x4 _ac[4]; _ac[0]=_ini; _ac[1]=_ini; _ac[2]=_ini; _ac[3]=_ini;                 \
    _Pragma("unroll") for (int _k=0;_k<6;++_k)                                        \
      _Pragma("unroll") for (int _m=0;_m<4;++_m)                                      \
        _ac[_m] = __builtin_amdgcn_mfma_f32_16x16x32_f16(CUR[_k], PA[_k][_m], _ac[_m],0,0,0); \
    _Pragma("unroll") for (int _m=0;_m<4;++_m) {                                      \
      const int _tok = 16*_m + l15;                                                   \
      if (_tok < NTOK) {                                                              \
        float4 _o = make_float4(_ac[_m][0], _ac[_m][1], _ac[_m][2], _ac[_m][3]);      \
        *(float4*)&og[(size_t)_tok*CDIM + (p0+(s))*16 + 4*lg] = _o; } } }

__global__ __launch_bounds__(256)
void winattn_core(const float* __restrict__ x,
                  const float* __restrict__ qkv_b,
                  const float* __restrict__ proj_b,
                  const u16* __restrict__ ws,
                  float* __restrict__ out)
{
    __shared__ __align__(16) u16 arena[ARENA_U16];
    const int b    = blockIdx.x;
    const int tid  = threadIdx.x;
    const int lane = tid & 63;
    const int wv   = tid >> 6;
    const int l15  = lane & 15;
    const int lg   = lane >> 4;
    const int win  = b & 63;

    const u16* wq = ws + WS_WQ;
    const int t0 = wv * 9;

    // ---- issue first 2 B tiles + bm early (global, independent of LDS) ----
    f16x8 Ba[6], Bb[6], Bc[6];
    LDFRAG(Ba, wq, t0); LDFRAG(Bb, wq, t0+1);
    f16x8 bmf[6][2];
    {
        const u16* bmb = ws + WS_BM + (((size_t)win*NH)*256 + tid)*16;
        #pragma unroll
        for (int h = 0; h < NH; ++h) {
            bmf[h][0] = *(const f16x8*)(bmb + h*4096);
            bmf[h][1] = *(const f16x8*)(bmb + h*4096 + 8);
        }
    }

    // ---- stage x fp32 via global_load_lds: linear dest, inverse-swizzled source ----
    // LDS granule p (16B) holds x granule r*48 + (c ^ (r&7)), r=p/48, c=p%48.
    {
        const float* xb = x + (size_t)b * (NTOK * CDIM);
        for (int i = wv; i < 37; i += 4) {
            const int p = i*64 + lane;
            if (p < 2352) {
                const int r = p / 48;
                const int c = p - r*48;
                const int g = r*48 + (c ^ (r & 7));
                gload16(xb + g*4, &arena[i*512]);
            }
        }
        for (int i = tid; i < CDIM * 4; i += 256)
            arena[VTOFF + (i >> 2) * VTSTR + 52 + (i & 3)] = 0;   // V^T pad cols 52..55
    }
    __syncthreads();   // x resident (syncthreads drains vmcnt incl. global_load_lds)

    // ---- A-frags: fp32 LDS (swizzled read) -> fp16 regs ----
    f16x8 A[6][4];
    #pragma unroll
    for (int m = 0; m < 4; ++m) {
        const int rr0 = 16*m + l15;
        const int rr = rr0 < NTOK ? rr0 : NTOK-1;
        const int sxr = rr & 7;
        const int gb = rr * 48;
        #pragma unroll
        for (int k6 = 0; k6 < 6; ++k6) {
            const int c0 = k6*8 + 2*lg;
            const float4 f0 = *(const float4*)&arena[(gb + (c0 ^ sxr)) * 8];
            const float4 f1 = *(const float4*)&arena[(gb + ((c0+1) ^ sxr)) * 8];
            const uint4 u = make_uint4(pk2(f0.x,f0.y), pk2(f0.z,f0.w),
                                       pk2(f1.x,f1.y), pk2(f1.z,f1.w));
            A[k6][m] = __builtin_bit_cast(f16x8, u);
        }
    }
    __syncthreads();   // all waves done reading x; Q/K region reusable

    // ---- QKV GEMM: A in regs, 9 tiles, 3-deep B rotation ----
    QKV_STEP(0, Ba, Bc, 1)
    QKV_STEP(1, Bb, Ba, 1)
    QKV_STEP(2, Bc, Bb, 1)
    QKV_STEP(3, Ba, Bc, 1)
    QKV_STEP(4, Bb, Ba, 1)
    QKV_STEP(5, Bc, Bb, 1)
    QKV_STEP(6, Ba, Bc, 1)
    QKV_STEP(7, Bb, Ba, 0)
    QKV_STEP(8, Bc, Bb, 0)

    __syncthreads();   // Q/K/VT visible

    // ---- proj B-tile + bias + arow issued early (hide under attention) ----
    const u16* wp = ws + WS_WP;
    const int p0 = wv * 3;
    f16x8 Pa[6], Pb2[6];
    LDFRAG(Pa, wp, p0);
    float4 pb4[3];
    #pragma unroll
    for (int s = 0; s < 3; ++s)
        pb4[s] = *(const float4*)&proj_b[(p0+s)*16 + 4*lg];
    int arow[4];
    #pragma unroll
    for (int m = 0; m < 4; ++m) {
        const int r = 16*m + l15;
        arow[m] = (r < NTOK ? r : NTOK-1) * QSTR;
    }

    // ---- attention: barrier-free; wave owns rows i0..i0+15 ----
    const int i0 = 16 * wv;
    const bool myok = (i0 + l15 < NTOK);
    const int myrow = myok ? i0 + l15 : NTOK-1;
    int krow[4];
    #pragma unroll
    for (int jt = 0; jt < 4; ++jt)
        krow[jt] = (jt*16 + l15 < NTOK ? jt*16 + l15 : NTOK-1) * QSTR;

    f16x8 Qf[6];
    #pragma unroll
    for (int h = 0; h < NH; ++h)
        Qf[h] = *(const f16x8*)&arena[QOFF + myrow*QSTR + h*HD + 8*lg];

    #pragma unroll
    for (int h = 0; h < NH; ++h) {
        u16* pp = arena + POFF + wv*2336 + (h & 1)*1168;   // wave-private P ping-pong
        // QK^T swapped: D col=lane=i, regs=j (logits already in log2 domain)
        f32x4 pacc[4];
        #pragma unroll
        for (int jt = 0; jt < 4; ++jt) {
            const f16x8 Kf = *(const f16x8*)&arena[KOFF + krow[jt] + h*HD + 8*lg];
            f32x4 z = {};
            pacc[jt] = __builtin_amdgcn_mfma_f32_16x16x32_f16(Kf, Qf[h], z, 0, 0, 0);
        }
        // softmax (base-2): 16 in-thread values + 2 shfls
        float val[4][4];
        float mx = -3e38f;
        #pragma unroll
        for (int jt = 0; jt < 4; ++jt)
            #pragma unroll
            for (int r = 0; r < 4; ++r) {
                val[jt][r] = pacc[jt][r] + (float)bmf[h][jt>>1][(jt&1)*4 + r];
                mx = fmaxf(mx, val[jt][r]);
            }
        mx = fmaxf(mx, __shfl_xor(mx, 16));
        mx = fmaxf(mx, __shfl_xor(mx, 32));
        float s = 0.f;
        #pragma unroll
        for (int jt = 0; jt < 4; ++jt)
            #pragma unroll
            for (int r = 0; r < 4; ++r) {
                const float e = exp2f(val[jt][r] - mx);
                val[jt][r] = e; s += e;
            }
        s += __shfl_xor(s, 16);
        s += __shfl_xor(s, 32);
        const float inv = 1.0f / s;
        // P~ (unnormalized) -> private LDS, packed b64
        #pragma unroll
        for (int jt = 0; jt < 4; ++jt)
            *(uint2*)&pp[l15*PSTR + jt*16 + 4*lg] =
                make_uint2(pk2(val[jt][0], val[jt][1]), pk2(val[jt][2], val[jt][3]));
        // PV swapped: A=V^T, B=P~; normalize at epilogue
        const f16x8 Pb0 = *(const f16x8*)&pp[l15*PSTR + 8*lg];
        const f16x8 Pb1 = *(const f16x8*)&pp[l15*PSTR + 32 + 8*lg];
        const int a1 = (32 + 8*lg <= 48) ? 32 + 8*lg : 48;   // clamp; pad zeroed, P=0
        #pragma unroll
        for (int nt = 0; nt < 2; ++nt) {
            const int vr = (h*HD + nt*16 + l15) * VTSTR;
            const f16x8 Va0 = *(const f16x8*)&arena[VTOFF + vr + 8*lg];
            const f16x8 Va1 = *(const f16x8*)&arena[VTOFF + vr + a1];
            f32x4 o = {};
            o = __builtin_amdgcn_mfma_f32_16x16x32_f16(Va0, Pb0, o, 0, 0, 0);
            o = __builtin_amdgcn_mfma_f32_16x16x32_f16(Va1, Pb1, o, 0, 0, 0);
            if (myok) {   // attnout -> dead Q region (own rows)
                *(uint2*)&arena[QOFF + (i0+l15)*QSTR + h*HD + nt*16 + 4*lg] =
                    make_uint2(pk2(o[0]*inv, o[1]*inv), pk2(o[2]*inv, o[3]*inv));
            }
        }
    }

    __syncthreads();   // all attnout rows visible
    {
        f16x8 PA[6][4];
        #pragma unroll
        for (int k6 = 0; k6 < 6; ++k6)
            #pragma unroll
            for (int m = 0; m < 4; ++m)
                PA[k6][m] = *(const f16x8*)&arena[QOFF + arow[m] + k6*32 + 8*lg];
        float* og = out + (size_t)b * (NTOK * CDIM);
        PROJ_STEP(0, Pa, Pb2, 1)
        PROJ_STEP(1, Pb2, Pa, 1)
        PROJ_STEP(2, Pa, Pb2, 0)
    }
}

extern "C" void kernel_launch(void* const* d_in, const int* in_sizes, int n_in,
                              void* d_out, int out_size, void* d_ws, size_t ws_size,
                              hipStream_t stream) {
    const float* x      = (const float*)d_in[0];
    const float* mask   = (const float*)d_in[1];
    const float* qkv_w  = (const float*)d_in[2];
    const float* qkv_b  = (const float*)d_in[3];
    const float* proj_w = (const float*)d_in[4];
    const float* proj_b = (const float*)d_in[5];
    const float* rpb    = (const float*)d_in[6];
    const int*   rel    = (const int*)d_in[7];
    u16* ws = (u16*)d_ws;

    const int nwin = in_sizes[0] / (NTOK * CDIM);          // 4096
    prep_weights<<<576, 256, 0, stream>>>(qkv_w, proj_w, ws);
    prep_bm<<<(64*NH*256*16 + 255)/256, 256, 0, stream>>>(mask, rpb, rel, ws);
    winattn_core<<<nwin, 256, 0, stream>>>(x, qkv_b, proj_b, ws, (float*)d_out);
}

// Round 15
// 165.628 us; speedup vs baseline: 1.5984x; 1.5984x over previous
//
#include <hip/hip_runtime.h>

typedef unsigned short u16;
typedef unsigned int   u32;
typedef _Float16 f16x8 __attribute__((ext_vector_type(8)));
typedef __fp16   hf2   __attribute__((ext_vector_type(2)));
typedef float    f32x4 __attribute__((ext_vector_type(4)));

#define NTOK 49
#define CDIM 192
#define NH   6
#define HD   32
#define SC   0.17677669529663687f
#define LOG2E 1.4426950408889634f

// ---- LDS arena (u16 units) ----
// x fp32 (49x192 = 37,632 B, granule-swizzled) overlays Q+K regions during staging;
// consumed into registers before QKV writes (extra barrier).
#define QOFF   0
#define QSTR   200            // 400 B stride
#define KOFF   9800
#define VTOFF  19600
#define VTSTR  56             // 112 B
#define POFF   30352          // per-wave P ping-pong: wv*2336 + (h&1)*1168
#define PSTR   72
#define ARENA_U16 40152       // 80,304 B -> 2 blocks/CU

// ---- ws layout (u16 units) ----
#define WS_WQ 0               // qkv weights frag-major: [(t*6+k6)*512 + lane*8 + e]; Q pre-scaled by SC*LOG2E
#define WS_WP 110592          // proj weights, same scheme
#define WS_BM 147456          // bias+mask per-thread (x LOG2E): [w][h][tid(256)][jt(4)][r(4)]

static __device__ __forceinline__ u16 f2h(float f){ union{ _Float16 h; u16 u;} v; v.h=(_Float16)f; return v.u; }
static __device__ __forceinline__ u32 pk2(float a, float b){
    hf2 h = __builtin_amdgcn_cvt_pkrtz(a, b);
    return __builtin_bit_cast(u32, h);
}
static __device__ __forceinline__ void gload16(const float* g, u16* l){
    __builtin_amdgcn_global_load_lds(
        (const __attribute__((address_space(1))) unsigned int*)g,
        (__attribute__((address_space(3))) unsigned int*)l, 16, 0, 0);
}

// ---------------- prep ----------------
__global__ void prep_weights(const float* __restrict__ qkv_w,
                             const float* __restrict__ proj_w,
                             u16* __restrict__ ws)
{
    const int idx = blockIdx.x*256 + threadIdx.x;
    if (idx < 110592) {
        const int fid = idx >> 9, r = idx & 511;
        const int lane = r >> 3, e = r & 7;
        const int t = fid/6, k6 = fid - 6*t;
        const int col = t*16 + (lane & 15);
        const int kk  = k6*32 + (lane >> 4)*8 + e;
        float w = qkv_w[col*CDIM + kk];
        if (col < CDIM) w *= SC * LOG2E;    // fold softmax scale + log2e into Q weights
        ws[WS_WQ + idx] = f2h(w);
    } else if (idx < 147456) {
        const int j = idx - 110592;
        const int fid = j >> 9, r = j & 511;
        const int lane = r >> 3, e = r & 7;
        const int t = fid/6, k6 = fid - 6*t;
        const int col = t*16 + (lane & 15);
        const int kk  = k6*32 + (lane >> 4)*8 + e;
        ws[WS_WP + j] = f2h(proj_w[col*CDIM + kk]);
    }
}

// thread tid of wave wv handles q-row i=16*(tid>>6)+(tid&15), j = jt*16 + 4*((tid>>4)&3) + r
__global__ void prep_bm(const float* __restrict__ mask,
                        const float* __restrict__ rpb,
                        const int*   __restrict__ rel,
                        u16* __restrict__ ws)
{
    const int idx = blockIdx.x*256 + threadIdx.x;
    if (idx >= 64*NH*256*16) return;
    const int r   = idx & 3;
    const int jt  = (idx >> 2) & 3;
    const int tid = (idx >> 4) & 255;
    const int rest = idx >> 12;
    const int h = rest % NH;
    const int w = rest / NH;
    const int i  = 16*(tid >> 6) + (tid & 15);
    const int lg = (tid >> 4) & 3;
    const int j  = jt*16 + 4*lg + r;
    float v;
    if (i >= NTOK)      v = 0.0f;
    else if (j >= NTOK) v = -1e30f;        // -> fp16 -inf; exp2 -> 0
    else v = (rpb[rel[i*NTOK+j]*NH + h] + mask[((size_t)w*NTOK+i)*NTOK + j]) * LOG2E;
    ws[WS_BM + idx] = f2h(v);
}

// ---------------- fused core ----------------
#define LDFRAG(B, BASE, t) { const u16* _p = (BASE) + (size_t)(t)*3072 + lane*8;      \
    B[0]=*(const f16x8*)(_p);      B[1]=*(const f16x8*)(_p+512);                      \
    B[2]=*(const f16x8*)(_p+1024); B[3]=*(const f16x8*)(_p+1536);                     \
    B[4]=*(const f16x8*)(_p+2048); B[5]=*(const f16x8*)(_p+2560); }

#define QKV_STEP(s, CUR, NXT, PF) {                                                   \
    if (PF) { LDFRAG(NXT, wq, t0+(s)+2); }                                            \
    const int _t = t0+(s); const int _sec = _t/12; const int _cb = (_t - _sec*12)*16; \
    f32x4 _ac[4];                                                                     \
    if (_sec < 2) {  /* Q/K swapped: token=lane, channel=reg; bias in acc-init */     \
      float4 _b4 = *(const float4*)&qkv_b[_t*16 + 4*lg];                              \
      if (_sec == 0) { _b4.x*=SC*LOG2E; _b4.y*=SC*LOG2E; _b4.z*=SC*LOG2E; _b4.w*=SC*LOG2E; } \
      const f32x4 _ini = {_b4.x, _b4.y, _b4.z, _b4.w};                                \
      _ac[0]=_ini; _ac[1]=_ini; _ac[2]=_ini; _ac[3]=_ini;                             \
      _Pragma("unroll") for (int _k=0;_k<6;++_k)                                      \
        _Pragma("unroll") for (int _m=0;_m<4;++_m)                                    \
          _ac[_m] = __builtin_amdgcn_mfma_f32_16x16x32_f16(CUR[_k], A[_k][_m], _ac[_m],0,0,0); \
      u16* _dst = (_sec==0) ? (arena+QOFF) : (arena+KOFF);                            \
      _Pragma("unroll") for (int _m=0;_m<4;++_m) {                                    \
        const int _tok = 16*_m + l15;                                                 \
        if (_tok < NTOK) {                                                            \
          uint2 _wd = make_uint2(pk2(_ac[_m][0], _ac[_m][1]),                         \
                                 pk2(_ac[_m][2], _ac[_m][3]));                        \
          *(uint2*)&_dst[_tok*QSTR + _cb + 4*lg] = _wd; } }                           \
    } else {         /* V normal: token=reg -> packed V^T writes */                   \
      const float _b1 = qkv_b[384 + _cb + l15];                                       \
      const f32x4 _ini = {_b1, _b1, _b1, _b1};                                        \
      _ac[0]=_ini; _ac[1]=_ini; _ac[2]=_ini; _ac[3]=_ini;                             \
      _Pragma("unroll") for (int _k=0;_k<6;++_k)                                      \
        _Pragma("unroll") for (int _m=0;_m<4;++_m)                                    \
          _ac[_m] = __builtin_amdgcn_mfma_f32_16x16x32_f16(A[_k][_m], CUR[_k], _ac[_m],0,0,0); \
      _Pragma("unroll") for (int _m=0;_m<4;++_m) {                                    \
        if (16*_m + 4*lg <= 48) {                                                     \
          uint2 _wd = make_uint2(pk2(_ac[_m][0], _ac[_m][1]),                         \
                                 pk2(_ac[_m][2], _ac[_m][3]));                        \
          *(uint2*)&arena[VTOFF + (_cb + l15)*VTSTR + 16*_m + 4*lg] = _wd; } } } }

#define PROJ_STEP(s, CUR, NXT, PF) {                                                  \
    if (PF) { LDFRAG(NXT, wp, p0+(s)+1); }                                            \
    const f32x4 _ini = {pb4[s].x, pb4[s].y, pb4[s].z, pb4[s].w};                      \
    f32x4 _ac[4]; _ac[0]=_ini; _ac[1]=_ini; _ac[2]=_ini; _ac[3]=_ini;                 \
    _Pragma("unroll") for (int _k=0;_k<6;++_k)                                        \
      _Pragma("unroll") for (int _m=0;_m<4;++_m)                                      \
        _ac[_m] = __builtin_amdgcn_mfma_f32_16x16x32_f16(CUR[_k], PA[_k][_m], _ac[_m],0,0,0); \
    _Pragma("unroll") for (int _m=0;_m<4;++_m) {                                      \
      const int _tok = 16*_m + l15;                                                   \
      if (_tok < NTOK) {                                                              \
        float4 _o = make_float4(_ac[_m][0], _ac[_m][1], _ac[_m][2], _ac[_m][3]);      \
        *(float4*)&og[(size_t)_tok*CDIM + (p0+(s))*16 + 4*lg] = _o; } } }

__global__ __launch_bounds__(256)
__attribute__((amdgpu_waves_per_eu(2, 2)))
void winattn_core(const float* __restrict__ x,
                  const float* __restrict__ qkv_b,
                  const float* __restrict__ proj_b,
                  const u16* __restrict__ ws,
                  float* __restrict__ out)
{
    __shared__ __align__(16) u16 arena[ARENA_U16];
    const int b    = blockIdx.x;
    const int tid  = threadIdx.x;
    const int lane = tid & 63;
    const int wv   = tid >> 6;
    const int l15  = lane & 15;
    const int lg   = lane >> 4;
    const int win  = b & 63;

    const u16* wq = ws + WS_WQ;
    const int t0 = wv * 9;

    // ---- issue first 2 B tiles + bm early (global, independent of LDS) ----
    f16x8 Ba[6], Bb[6], Bc[6];
    LDFRAG(Ba, wq, t0); LDFRAG(Bb, wq, t0+1);
    f16x8 bmf[6][2];
    {
        const u16* bmb = ws + WS_BM + (((size_t)win*NH)*256 + tid)*16;
        #pragma unroll
        for (int h = 0; h < NH; ++h) {
            bmf[h][0] = *(const f16x8*)(bmb + h*4096);
            bmf[h][1] = *(const f16x8*)(bmb + h*4096 + 8);
        }
    }

    // ---- stage x fp32 via global_load_lds: linear dest, inverse-swizzled source ----
    // LDS granule p (16B) holds x granule r*48 + (c ^ (r&7)), r=p/48, c=p%48.
    {
        const float* xb = x + (size_t)b * (NTOK * CDIM);
        for (int i = wv; i < 37; i += 4) {
            const int p = i*64 + lane;
            if (p < 2352) {
                const int r = p / 48;
                const int c = p - r*48;
                const int g = r*48 + (c ^ (r & 7));
                gload16(xb + g*4, &arena[i*512]);
            }
        }
        for (int i = tid; i < CDIM * 4; i += 256)
            arena[VTOFF + (i >> 2) * VTSTR + 52 + (i & 3)] = 0;   // V^T pad cols 52..55
    }
    __syncthreads();   // x resident (syncthreads drains vmcnt incl. global_load_lds)

    // ---- A-frags: fp32 LDS (swizzled read) -> fp16 regs ----
    f16x8 A[6][4];
    #pragma unroll
    for (int m = 0; m < 4; ++m) {
        const int rr0 = 16*m + l15;
        const int rr = rr0 < NTOK ? rr0 : NTOK-1;
        const int sxr = rr & 7;
        const int gb = rr * 48;
        #pragma unroll
        for (int k6 = 0; k6 < 6; ++k6) {
            const int c0 = k6*8 + 2*lg;
            const float4 f0 = *(const float4*)&arena[(gb + (c0 ^ sxr)) * 8];
            const float4 f1 = *(const float4*)&arena[(gb + ((c0+1) ^ sxr)) * 8];
            const uint4 u = make_uint4(pk2(f0.x,f0.y), pk2(f0.z,f0.w),
                                       pk2(f1.x,f1.y), pk2(f1.z,f1.w));
            A[k6][m] = __builtin_bit_cast(f16x8, u);
        }
    }
    __syncthreads();   // all waves done reading x; Q/K region reusable

    // ---- QKV GEMM: A in regs, 9 tiles, 3-deep B rotation ----
    QKV_STEP(0, Ba, Bc, 1)
    QKV_STEP(1, Bb, Ba, 1)
    QKV_STEP(2, Bc, Bb, 1)
    QKV_STEP(3, Ba, Bc, 1)
    QKV_STEP(4, Bb, Ba, 1)
    QKV_STEP(5, Bc, Bb, 1)
    QKV_STEP(6, Ba, Bc, 1)
    QKV_STEP(7, Bb, Ba, 0)
    QKV_STEP(8, Bc, Bb, 0)

    __syncthreads();   // Q/K/VT visible

    // ---- proj B-tile + bias + arow issued early (hide under attention) ----
    const u16* wp = ws + WS_WP;
    const int p0 = wv * 3;
    f16x8 Pa[6], Pb2[6];
    LDFRAG(Pa, wp, p0);
    float4 pb4[3];
    #pragma unroll
    for (int s = 0; s < 3; ++s)
        pb4[s] = *(const float4*)&proj_b[(p0+s)*16 + 4*lg];
    int arow[4];
    #pragma unroll
    for (int m = 0; m < 4; ++m) {
        const int r = 16*m + l15;
        arow[m] = (r < NTOK ? r : NTOK-1) * QSTR;
    }

    // ---- attention: barrier-free; wave owns rows i0..i0+15 ----
    const int i0 = 16 * wv;
    const bool myok = (i0 + l15 < NTOK);
    const int myrow = myok ? i0 + l15 : NTOK-1;
    int krow[4];
    #pragma unroll
    for (int jt = 0; jt < 4; ++jt)
        krow[jt] = (jt*16 + l15 < NTOK ? jt*16 + l15 : NTOK-1) * QSTR;

    f16x8 Qf[6];
    #pragma unroll
    for (int h = 0; h < NH; ++h)
        Qf[h] = *(const f16x8*)&arena[QOFF + myrow*QSTR + h*HD + 8*lg];

    #pragma unroll
    for (int h = 0; h < NH; ++h) {
        u16* pp = arena + POFF + wv*2336 + (h & 1)*1168;   // wave-private P ping-pong
        // QK^T swapped: D col=lane=i, regs=j (logits already in log2 domain)
        f32x4 pacc[4];
        #pragma unroll
        for (int jt = 0; jt < 4; ++jt) {
            const f16x8 Kf = *(const f16x8*)&arena[KOFF + krow[jt] + h*HD + 8*lg];
            f32x4 z = {};
            pacc[jt] = __builtin_amdgcn_mfma_f32_16x16x32_f16(Kf, Qf[h], z, 0, 0, 0);
        }
        // softmax (base-2): 16 in-thread values + 2 shfls
        float val[4][4];
        float mx = -3e38f;
        #pragma unroll
        for (int jt = 0; jt < 4; ++jt)
            #pragma unroll
            for (int r = 0; r < 4; ++r) {
                val[jt][r] = pacc[jt][r] + (float)bmf[h][jt>>1][(jt&1)*4 + r];
                mx = fmaxf(mx, val[jt][r]);
            }
        mx = fmaxf(mx, __shfl_xor(mx, 16));
        mx = fmaxf(mx, __shfl_xor(mx, 32));
        float s = 0.f;
        #pragma unroll
        for (int jt = 0; jt < 4; ++jt)
            #pragma unroll
            for (int r = 0; r < 4; ++r) {
                const float e = exp2f(val[jt][r] - mx);
                val[jt][r] = e; s += e;
            }
        s += __shfl_xor(s, 16);
        s += __shfl_xor(s, 32);
        const float inv = 1.0f / s;
        // P~ (unnormalized) -> private LDS, packed b64
        #pragma unroll
        for (int jt = 0; jt < 4; ++jt)
            *(uint2*)&pp[l15*PSTR + jt*16 + 4*lg] =
                make_uint2(pk2(val[jt][0], val[jt][1]), pk2(val[jt][2], val[jt][3]));
        // PV swapped: A=V^T, B=P~; normalize at epilogue
        const f16x8 Pb0 = *(const f16x8*)&pp[l15*PSTR + 8*lg];
        const f16x8 Pb1 = *(const f16x8*)&pp[l15*PSTR + 32 + 8*lg];
        const int a1 = (32 + 8*lg <= 48) ? 32 + 8*lg : 48;   // clamp; pad zeroed, P=0
        #pragma unroll
        for (int nt = 0; nt < 2; ++nt) {
            const int vr = (h*HD + nt*16 + l15) * VTSTR;
            const f16x8 Va0 = *(const f16x8*)&arena[VTOFF + vr + 8*lg];
            const f16x8 Va1 = *(const f16x8*)&arena[VTOFF + vr + a1];
            f32x4 o = {};
            o = __builtin_amdgcn_mfma_f32_16x16x32_f16(Va0, Pb0, o, 0, 0, 0);
            o = __builtin_amdgcn_mfma_f32_16x16x32_f16(Va1, Pb1, o, 0, 0, 0);
            if (myok) {   // attnout -> dead Q region (own rows)
                *(uint2*)&arena[QOFF + (i0+l15)*QSTR + h*HD + nt*16 + 4*lg] =
                    make_uint2(pk2(o[0]*inv, o[1]*inv), pk2(o[2]*inv, o[3]*inv));
            }
        }
    }

    __syncthreads();   // all attnout rows visible
    {
        f16x8 PA[6][4];
        #pragma unroll
        for (int k6 = 0; k6 < 6; ++k6)
            #pragma unroll
            for (int m = 0; m < 4; ++m)
                PA[k6][m] = *(const f16x8*)&arena[QOFF + arow[m] + k6*32 + 8*lg];
        float* og = out + (size_t)b * (NTOK * CDIM);
        PROJ_STEP(0, Pa, Pb2, 1)
        PROJ_STEP(1, Pb2, Pa, 1)
        PROJ_STEP(2, Pa, Pb2, 0)
    }
}

extern "C" void kernel_launch(void* const* d_in, const int* in_sizes, int n_in,
                              void* d_out, int out_size, void* d_ws, size_t ws_size,
                              hipStream_t stream) {
    const float* x      = (const float*)d_in[0];
    const float* mask   = (const float*)d_in[1];
    const float* qkv_w  = (const float*)d_in[2];
    const float* qkv_b  = (const float*)d_in[3];
    const float* proj_w = (const float*)d_in[4];
    const float* proj_b = (const float*)d_in[5];
    const float* rpb    = (const float*)d_in[6];
    const int*   rel    = (const int*)d_in[7];
    u16* ws = (u16*)d_ws;

    const int nwin = in_sizes[0] / (NTOK * CDIM);          // 4096
    prep_weights<<<576, 256, 0, stream>>>(qkv_w, proj_w, ws);
    prep_bm<<<(64*NH*256*16 + 255)/256, 256, 0, stream>>>(mask, rpb, rel, ws);
    winattn_core<<<nwin, 256, 0, stream>>>(x, qkv_b, proj_b, ws, (float*)d_out);
}